// Round 7
// baseline (1133.197 us; speedup 1.0000x reference)
//
#include <hip/hip_runtime.h>
#include <hip/hip_bf16.h>

#define NFEAT 128
#define EPB 4096  // edges per binning block (1024 thr x 4)

typedef __attribute__((ext_vector_type(8))) short bf16x8;
typedef __attribute__((ext_vector_type(4))) float f32x4;

__device__ inline unsigned short f2bf(float f) {  // RNE f32 -> bf16
    unsigned int u = __float_as_uint(f);
    u += 0x7fffu + ((u >> 16) & 1u);
    return (unsigned short)(u >> 16);
}
__device__ inline unsigned int pack2bf(float lo, float hi) {
    return (unsigned int)f2bf(lo) | ((unsigned int)f2bf(hi) << 16);
}
__device__ inline float bflo(unsigned int v) {
    return __uint_as_float((v & 0xffffu) << 16);
}
__device__ inline float bfhi(unsigned int v) {
    return __uint_as_float(v & 0xffff0000u);
}

// ---------------------------------------------------------------------------
// fused prep: convert h->bf16  |  pack+transpose weights
// ---------------------------------------------------------------------------
__global__ void prep_kernel(const float* __restrict__ h,
                            const float* __restrict__ Ws0,
                            const float* __restrict__ Wn0,
                            const float* __restrict__ Ws1,
                            const float* __restrict__ Wn1,
                            unsigned short* __restrict__ hbf,
                            unsigned short* __restrict__ WcT, int n4, int nw) {
    int i = blockIdx.x * blockDim.x + threadIdx.x;
    if (i < n4) {  // convert 4 f32 -> 4 bf16
        float4 v = reinterpret_cast<const float4*>(h)[i];
        uint2 o;
        o.x = pack2bf(v.x, v.y);
        o.y = pack2bf(v.z, v.w);
        reinterpret_cast<uint2*>(hbf)[i] = o;
    } else if (i < n4 + nw) {  // weights: WcT[layer][j][k]
        int idx = i - n4;
        int layer = idx >> 15;
        int rem = idx & 32767;
        int j = rem >> 8;
        int k = rem & 255;
        const float* Ws = layer ? Ws1 : Ws0;
        const float* Wn = layer ? Wn1 : Wn0;
        float v = (k < 128) ? Ws[k * 128 + j] : Wn[(k - 128) * 128 + j];
        WcT[layer * 32768 + j * 256 + k] = f2bf(v);
    }
}

// ---------------------------------------------------------------------------
// binning pass 1: per-block LDS histogram of bucket = dst>>7 (B <= 512)
// ---------------------------------------------------------------------------
__global__ __launch_bounds__(1024) void bin_hist_kernel(
    const int* __restrict__ dst, int* __restrict__ Hist, int n_edges, int B) {
    __shared__ int sH[512];
    const int tid = threadIdx.x;
    const int blk = blockIdx.x;
    if (tid < 512) sH[tid] = 0;
    __syncthreads();
#pragma unroll
    for (int i = 0; i < 4; ++i) {
        int e = blk * EPB + i * 1024 + tid;
        if (e < n_edges) atomicAdd(&sH[dst[e] >> 7], 1);
    }
    __syncthreads();
    if (tid < B) Hist[blk * B + tid] = sH[tid];
}

// ---------------------------------------------------------------------------
// binning pass 2 (single block): Hist[blk][b] -> global offsets (in place),
// bucket_base[b] = exclusive prefix of bucket totals, bucket_base[B] = E.
// ---------------------------------------------------------------------------
__global__ __launch_bounds__(512) void bin_scan_kernel(
    int* __restrict__ Hist, int* __restrict__ bucket_base, int nblkE, int B) {
    __shared__ int s[512];
    const int b = threadIdx.x;
    int run = 0;
    if (b < B) {
        int blk = 0;
        for (; blk + 4 <= nblkE; blk += 4) {
            int h0 = Hist[(blk + 0) * B + b];
            int h1 = Hist[(blk + 1) * B + b];
            int h2 = Hist[(blk + 2) * B + b];
            int h3 = Hist[(blk + 3) * B + b];
            Hist[(blk + 0) * B + b] = run;
            Hist[(blk + 1) * B + b] = run + h0;
            Hist[(blk + 2) * B + b] = run + h0 + h1;
            Hist[(blk + 3) * B + b] = run + h0 + h1 + h2;
            run += h0 + h1 + h2 + h3;
        }
        for (; blk < nblkE; ++blk) {
            int h = Hist[blk * B + b];
            Hist[blk * B + b] = run;
            run += h;
        }
    }
    s[b] = (b < B) ? run : 0;
    __syncthreads();
    for (int off = 1; off < 512; off <<= 1) {
        int t = (b >= off) ? s[b - off] : 0;
        __syncthreads();
        s[b] += t;
        __syncthreads();
    }
    if (b < B) {
        int excl = s[b] - run;
        bucket_base[b] = excl;
#pragma unroll 4
        for (int blk = 0; blk < nblkE; ++blk) Hist[blk * B + b] += excl;
    }
    if (b == 511) bucket_base[B] = s[511];
}

// ---------------------------------------------------------------------------
// binning pass 3: scatter packed records (dstlo<<20 | src) into bucket runs.
// Writes are contiguous per (block,bucket) -> L2 write-combining friendly.
// ---------------------------------------------------------------------------
__global__ __launch_bounds__(1024) void bin_scatter_kernel(
    const int* __restrict__ src, const int* __restrict__ dst,
    const int* __restrict__ Off, unsigned int* __restrict__ Binned,
    int n_edges, int B) {
    __shared__ int sOff[512];
    __shared__ int sCnt[512];
    const int tid = threadIdx.x;
    const int blk = blockIdx.x;
    if (tid < B) sOff[tid] = Off[blk * B + tid];
    if (tid < 512) sCnt[tid] = 0;
    __syncthreads();
#pragma unroll
    for (int i = 0; i < 4; ++i) {
        int e = blk * EPB + i * 1024 + tid;
        if (e < n_edges) {
            int d = dst[e];
            int b = d >> 7;
            int r = atomicAdd(&sCnt[b], 1);
            Binned[sOff[b] + r] =
                (unsigned)src[e] | ((unsigned)(d & 127) << 20);
        }
    }
}

// ---------------------------------------------------------------------------
// fused scatter-aggregate: one block per bucket (128 nodes), 64KB f32 LDS
// accumulator. One edge per wave per step, 4-deep unrolled; gather loads
// coalesced (uint/lane); LDS atomicAdd with parity-staggered addresses
// (2*lane + p, p=(lane>>4)&1) -> every ds_add covers 32 banks 2-way (free).
// ---------------------------------------------------------------------------
__global__ __launch_bounds__(256) void agg_kernel(
    const unsigned short* __restrict__ Xbf,
    const unsigned int* __restrict__ Binned,
    const int* __restrict__ bucket_base, unsigned short* __restrict__ Mbf,
    int n_nodes) {
    __shared__ float sAcc[128 * 128];
    __shared__ int sCnt[128];
    __shared__ float sInv[128];
    const int tid = threadIdx.x;
    const int bkt = blockIdx.x;

    for (int i = tid; i < 128 * 32; i += 256)
        reinterpret_cast<float4*>(sAcc)[i] = (float4){0.f, 0.f, 0.f, 0.f};
    if (tid < 128) sCnt[tid] = 0;
    __syncthreads();

    const int beg = bucket_base[bkt];
    const int end = bucket_base[bkt + 1];
    const int wave = tid >> 6;
    const int lane = tid & 63;
    const int p = (lane >> 4) & 1;

    for (int e0 = beg + wave * 4; e0 < end; e0 += 16) {
        unsigned rec[4];
#pragma unroll
        for (int u = 0; u < 4; ++u) rec[u] = Binned[min(e0 + u, end - 1)];
        unsigned v[4];
#pragma unroll
        for (int u = 0; u < 4; ++u) {
            int srcn = rec[u] & 0xFFFFF;
            v[u] = reinterpret_cast<const unsigned*>(
                Xbf + ((size_t)srcn << 7))[lane];
            if (e0 + u >= end) v[u] = 0;
        }
#pragma unroll
        for (int u = 0; u < 4; ++u) {
            int dstlo = (rec[u] >> 20) & 127;
            float lo = bflo(v[u]);
            float hi = bfhi(v[u]);
            float* rowp = sAcc + dstlo * 128 + 2 * lane;
            atomicAdd(rowp + p, p ? hi : lo);
            atomicAdd(rowp + (1 - p), p ? lo : hi);
            if (lane == 0 && e0 + u < end) atomicAdd(&sCnt[dstlo], 1);
        }
    }
    __syncthreads();
    if (tid < 128) sInv[tid] = 1.0f / fmaxf((float)sCnt[tid], 1.0f);
    __syncthreads();

    const int node0 = bkt << 7;
    for (int i = tid; i < 128 * 16; i += 256) {
        int n = i >> 4;
        int ch = i & 15;
        int gn = node0 + n;
        if (gn < n_nodes) {
            const float* rp = sAcc + n * 128 + ch * 8;
            float inv = sInv[n];
            uint4 o;
            o.x = pack2bf(rp[0] * inv, rp[1] * inv);
            o.y = pack2bf(rp[2] * inv, rp[3] * inv);
            o.z = pack2bf(rp[4] * inv, rp[5] * inv);
            o.w = pack2bf(rp[6] * inv, rp[7] * inv);
            reinterpret_cast<uint4*>(Mbf + ((size_t)gn << 7))[ch] = o;
        }
    }
}

// ---------------------------------------------------------------------------
// MFMA GEMM: out = [relu]( [Xbf | Mbf] @ WcT^T + b ),  K=256, 16x16x32 bf16.
// Block: 512 thr = 8 waves; wave w owns rows [blk*128 + w*16, +16) x all 128
// cols. Full weight layer (64KB) staged in LDS with 16B-chunk XOR swizzle
// (chunk' = chunk ^ (row&7)) -> B ds_read_b128 is 2-way/bank = conflict-free.
// A-fragments (own rows) hoisted to registers. 2 blocks/CU (LDS-limited).
// In-place out_bf==Xbf is safe: each wave writes only rows it alone read.
// ---------------------------------------------------------------------------
__global__ __launch_bounds__(512, 4) void mfma_gemm_kernel(
    const unsigned short* __restrict__ Xbf,  // [N,128] bf16
    const unsigned short* __restrict__ Mbf,  // [N,128] bf16
    const unsigned short* __restrict__ WcT,  // [128][256] bf16 (j-major)
    const float* __restrict__ bias,          // [128] f32
    unsigned short* out_bf,                  // bf16 out (or null)
    float* out_f32,                          // f32 out (or null)
    int n_nodes, int do_relu) {
    __shared__ unsigned short sW[128 * 256];  // 64 KB, swizzled

    const int tid = threadIdx.x;
    const int wave = tid >> 6;
    const int lane = tid & 63;

    // ---- stage WcT -> LDS (coalesced global read, swizzled ds_write) ----
#pragma unroll
    for (int it = 0; it < 8; ++it) {
        int c = it * 512 + tid;        // 16B-chunk id, 4096 total
        int row = c >> 5;              // 0..127
        int ch = c & 31;               // chunk within row
        bf16x8 v = *reinterpret_cast<const bf16x8*>(WcT + row * 256 + ch * 8);
        *reinterpret_cast<bf16x8*>(sW + row * 256 + ((ch ^ (row & 7)) << 3)) = v;
    }

    const int row_base = blockIdx.x * 128 + wave * 16;
    const int l15 = lane & 15;
    const int g = lane >> 4;       // 0..3
    const int kgrp = g * 8;        // k-offset within 32-wide k-step

    // ---- hoist A fragments (this wave's 16 rows, k=0..255) ----
    const int arow = min(row_base + l15, n_nodes - 1);
    const unsigned short* Arow = Xbf + (size_t)arow * NFEAT;
    const unsigned short* Mrow = Mbf + (size_t)arow * NFEAT;
    bf16x8 afr[8];
#pragma unroll
    for (int s = 0; s < 4; ++s)
        afr[s] = *reinterpret_cast<const bf16x8*>(Arow + s * 32 + kgrp);
#pragma unroll
    for (int s = 0; s < 4; ++s)
        afr[4 + s] = *reinterpret_cast<const bf16x8*>(Mrow + s * 32 + kgrp);

    f32x4 acc[8];
#pragma unroll
    for (int t = 0; t < 8; ++t) acc[t] = (f32x4){0.f, 0.f, 0.f, 0.f};

    __syncthreads();  // sW ready

#pragma unroll
    for (int ks = 0; ks < 8; ++ks) {  // k0 = ks*32
        const int chunk_w = ks * 4 + g;  // (k0 + kgrp)/8
#pragma unroll
        for (int t = 0; t < 8; ++t) {
            const int j = t * 16 + l15;
            bf16x8 b = *reinterpret_cast<const bf16x8*>(
                sW + j * 256 + ((chunk_w ^ (j & 7)) << 3));
            acc[t] =
                __builtin_amdgcn_mfma_f32_16x16x32_bf16(afr[ks], b, acc[t], 0, 0, 0);
        }
    }

    // C/D layout: col = lane&15, row = (lane>>4)*4 + reg
    const int crow0 = row_base + g * 4;
#pragma unroll
    for (int t = 0; t < 8; ++t) {
        const int c = t * 16 + l15;
        const float bj = bias[c];
#pragma unroll
        for (int r = 0; r < 4; ++r) {
            const int gr = crow0 + r;
            if (gr < n_nodes) {
                float v = acc[t][r] + bj;
                if (do_relu) v = fmaxf(v, 0.f);
                if (out_f32)
                    out_f32[(size_t)gr * NFEAT + c] = v;
                else
                    out_bf[(size_t)gr * NFEAT + c] = f2bf(v);
            }
        }
    }
}

extern "C" void kernel_launch(void* const* d_in, const int* in_sizes, int n_in,
                              void* d_out, int out_size, void* d_ws,
                              size_t ws_size, hipStream_t stream) {
    const float* h = (const float*)d_in[0];
    const int* src = (const int*)d_in[1];
    const int* dst = (const int*)d_in[2];
    const float* Ws0 = (const float*)d_in[3];
    const float* Wn0 = (const float*)d_in[4];
    const float* b0 = (const float*)d_in[5];
    const float* Ws1 = (const float*)d_in[6];
    const float* Wn1 = (const float*)d_in[7];
    const float* b1 = (const float*)d_in[8];
    float* out = (float*)d_out;

    const int n_nodes = in_sizes[0] / NFEAT;
    const int n_edges = in_sizes[1];
    const int B = (n_nodes + 127) >> 7;            // buckets (391 <= 512)
    const int nblkE = (n_edges + EPB - 1) / EPB;   // binning blocks (147)

    // workspace layout (~28.4 MB)
    unsigned short* hbf = (unsigned short*)d_ws;          // [N,128] bf16 (+h1)
    unsigned short* Mbf = hbf + (size_t)n_nodes * NFEAT;  // [N,128] bf16
    unsigned short* WcT = Mbf + (size_t)n_nodes * NFEAT;  // 2*[128][256] bf16
    int* Hist = (int*)(WcT + 2 * 128 * 256);              // [nblkE][B]
    int* bucket_base = Hist + (size_t)nblkE * B;          // [B+1]
    unsigned int* Binned = (unsigned int*)(bucket_base + B + 1);  // [E]

    // ---- prep (convert + weights) ----
    const int n4 = n_nodes * NFEAT / 4;
    const int nw = 2 * 128 * 256;
    prep_kernel<<<(n4 + nw + 255) / 256, 256, 0, stream>>>(
        h, Ws0, Wn0, Ws1, Wn1, hbf, WcT, n4, nw);

    // ---- coarse bucket binning ----
    bin_hist_kernel<<<nblkE, 1024, 0, stream>>>(dst, Hist, n_edges, B);
    bin_scan_kernel<<<1, 512, 0, stream>>>(Hist, bucket_base, nblkE, B);
    bin_scatter_kernel<<<nblkE, 1024, 0, stream>>>(src, dst, Hist, Binned,
                                                   n_edges, B);

    const int gemm_blocks = (n_nodes + 127) / 128;

    // ---- layer 0 (h1 bf16 written in-place over hbf) ----
    agg_kernel<<<B, 256, 0, stream>>>(hbf, Binned, bucket_base, Mbf, n_nodes);
    mfma_gemm_kernel<<<gemm_blocks, 512, 0, stream>>>(
        hbf, Mbf, WcT, b0, hbf, (float*)nullptr, n_nodes, 1);

    // ---- layer 1 (f32 out to d_out) ----
    agg_kernel<<<B, 256, 0, stream>>>(hbf, Binned, bucket_base, Mbf, n_nodes);
    mfma_gemm_kernel<<<gemm_blocks, 512, 0, stream>>>(
        hbf, Mbf, WcT + 32768, b1, (unsigned short*)nullptr, out, n_nodes, 0);
}

// Round 8
// 153.148 us; speedup vs baseline: 7.3993x; 7.3993x over previous
//
#include <hip/hip_runtime.h>
#include <hip/hip_bf16.h>

#define NFEAT 128
#define EPB 4096  // edges per binning block (1024 thr x 4)

typedef __attribute__((ext_vector_type(8))) short bf16x8;
typedef __attribute__((ext_vector_type(4))) float f32x4;

__device__ inline unsigned short f2bf(float f) {  // RNE f32 -> bf16
    unsigned int u = __float_as_uint(f);
    u += 0x7fffu + ((u >> 16) & 1u);
    return (unsigned short)(u >> 16);
}
__device__ inline unsigned int pack2bf(float lo, float hi) {
    return (unsigned int)f2bf(lo) | ((unsigned int)f2bf(hi) << 16);
}
__device__ inline float bf2f(unsigned short s) {
    return __uint_as_float(((unsigned int)s) << 16);
}

// ---------------------------------------------------------------------------
// fused prep: convert h->bf16  |  pack+transpose weights
// ---------------------------------------------------------------------------
__global__ void prep_kernel(const float* __restrict__ h,
                            const float* __restrict__ Ws0,
                            const float* __restrict__ Wn0,
                            const float* __restrict__ Ws1,
                            const float* __restrict__ Wn1,
                            unsigned short* __restrict__ hbf,
                            unsigned short* __restrict__ WcT, int n4, int nw) {
    int i = blockIdx.x * blockDim.x + threadIdx.x;
    if (i < n4) {
        float4 v = reinterpret_cast<const float4*>(h)[i];
        uint2 o;
        o.x = pack2bf(v.x, v.y);
        o.y = pack2bf(v.z, v.w);
        reinterpret_cast<uint2*>(hbf)[i] = o;
    } else if (i < n4 + nw) {
        int idx = i - n4;
        int layer = idx >> 15;
        int rem = idx & 32767;
        int j = rem >> 8;
        int k = rem & 255;
        const float* Ws = layer ? Ws1 : Ws0;
        const float* Wn = layer ? Wn1 : Wn0;
        float v = (k < 128) ? Ws[k * 128 + j] : Wn[(k - 128) * 128 + j];
        WcT[layer * 32768 + j * 256 + k] = f2bf(v);
    }
}

// ---------------------------------------------------------------------------
// binning pass 1: per-block LDS histogram of bucket = dst>>7 (B <= 512)
// ---------------------------------------------------------------------------
__global__ __launch_bounds__(1024) void bin_hist_kernel(
    const int* __restrict__ dst, int* __restrict__ Hist, int n_edges, int B) {
    __shared__ int sH[512];
    const int tid = threadIdx.x;
    const int blk = blockIdx.x;
    if (tid < 512) sH[tid] = 0;
    __syncthreads();
#pragma unroll
    for (int i = 0; i < 4; ++i) {
        int e = blk * EPB + i * 1024 + tid;
        if (e < n_edges) atomicAdd(&sH[dst[e] >> 7], 1);
    }
    __syncthreads();
    if (tid < B) Hist[blk * B + tid] = sH[tid];
}

// ---------------------------------------------------------------------------
// binning pass 2 (single block): Hist[blk][b] -> global offsets (in place),
// bucket_base[b] = exclusive prefix of bucket totals, bucket_base[B] = E.
// ---------------------------------------------------------------------------
__global__ __launch_bounds__(512) void bin_scan_kernel(
    int* __restrict__ Hist, int* __restrict__ bucket_base, int nblkE, int B) {
    __shared__ int s[512];
    const int b = threadIdx.x;
    int run = 0;
    if (b < B) {
        int blk = 0;
        for (; blk + 4 <= nblkE; blk += 4) {
            int h0 = Hist[(blk + 0) * B + b];
            int h1 = Hist[(blk + 1) * B + b];
            int h2 = Hist[(blk + 2) * B + b];
            int h3 = Hist[(blk + 3) * B + b];
            Hist[(blk + 0) * B + b] = run;
            Hist[(blk + 1) * B + b] = run + h0;
            Hist[(blk + 2) * B + b] = run + h0 + h1;
            Hist[(blk + 3) * B + b] = run + h0 + h1 + h2;
            run += h0 + h1 + h2 + h3;
        }
        for (; blk < nblkE; ++blk) {
            int h = Hist[blk * B + b];
            Hist[blk * B + b] = run;
            run += h;
        }
    }
    s[b] = (b < B) ? run : 0;
    __syncthreads();
    for (int off = 1; off < 512; off <<= 1) {
        int t = (b >= off) ? s[b - off] : 0;
        __syncthreads();
        s[b] += t;
        __syncthreads();
    }
    if (b < B) {
        int excl = s[b] - run;
        bucket_base[b] = excl;
#pragma unroll 4
        for (int blk = 0; blk < nblkE; ++blk) Hist[blk * B + b] += excl;
    }
    if (b == 511) bucket_base[B] = s[511];
}

// ---------------------------------------------------------------------------
// binning pass 3: scatter packed records (dstlo<<20 | src) into bucket runs.
// ---------------------------------------------------------------------------
__global__ __launch_bounds__(1024) void bin_scatter_kernel(
    const int* __restrict__ src, const int* __restrict__ dst,
    const int* __restrict__ Off, unsigned int* __restrict__ Binned,
    int n_edges, int B) {
    __shared__ int sOff[512];
    __shared__ int sCnt[512];
    const int tid = threadIdx.x;
    const int blk = blockIdx.x;
    if (tid < B) sOff[tid] = Off[blk * B + tid];
    if (tid < 512) sCnt[tid] = 0;
    __syncthreads();
#pragma unroll
    for (int i = 0; i < 4; ++i) {
        int e = blk * EPB + i * 1024 + tid;
        if (e < n_edges) {
            int d = dst[e];
            int b = d >> 7;
            int r = atomicAdd(&sCnt[b], 1);
            Binned[sOff[b] + r] =
                (unsigned)src[e] | ((unsigned)(d & 127) << 20);
        }
    }
}

// ---------------------------------------------------------------------------
// per-bucket CSR fill: one block per bucket (128 nodes). LDS histogram over
// dstlo -> 128-wide scan -> row_start (coalesced) + edge_src scatter confined
// to this bucket's ~6KB run (single block/XCD -> no false sharing).
// ---------------------------------------------------------------------------
__global__ __launch_bounds__(256) void csr_fill_kernel(
    const unsigned int* __restrict__ Binned,
    const int* __restrict__ bucket_base, int* __restrict__ edge_src,
    int* __restrict__ row_start, int n_nodes) {
    __shared__ int sH[128];
    __shared__ int sS[128];    // inclusive scan
    __shared__ int sCur[128];  // scatter cursor
    const int tid = threadIdx.x;
    const int bkt = blockIdx.x;
    const int beg = bucket_base[bkt];
    const int end = bucket_base[bkt + 1];

    if (tid < 128) sH[tid] = 0;
    __syncthreads();
    for (int e = beg + tid; e < end; e += 256)
        atomicAdd(&sH[(Binned[e] >> 20) & 127], 1);
    __syncthreads();
    if (tid < 128) sS[tid] = sH[tid];
    __syncthreads();
    for (int off = 1; off < 128; off <<= 1) {
        int v = (tid >= off && tid < 128) ? sS[tid - off] : 0;
        __syncthreads();
        if (tid < 128) sS[tid] += v;
        __syncthreads();
    }
    if (tid < 128) {
        int excl = sS[tid] - sH[tid];
        sCur[tid] = excl;
        int gn = (bkt << 7) + tid;
        if (gn <= n_nodes) row_start[gn] = beg + excl;
    }
    __syncthreads();
    for (int e = beg + tid; e < end; e += 256) {
        unsigned rec = Binned[e];
        int pos = beg + atomicAdd(&sCur[(rec >> 20) & 127], 1);
        edge_src[pos] = (int)(rec & 0xFFFFF);
    }
}

// ---------------------------------------------------------------------------
// mean aggregation, high-MLP form: one wave per node; quarter-wave per row.
// 16 rows in flight per wave; 2-step shfl_xor reduce; sub==0 writes 256B row.
// ---------------------------------------------------------------------------
__global__ __launch_bounds__(256) void aggregate_kernel(
    const unsigned short* __restrict__ Xbf, const int* __restrict__ row_start,
    const int* __restrict__ edge_src, unsigned short* __restrict__ Mbf,
    int n_nodes) {
    const int wave = (blockIdx.x * blockDim.x + threadIdx.x) >> 6;
    const int lane = threadIdx.x & 63;
    if (wave >= n_nodes) return;
    const int beg = row_start[wave];
    const int end = row_start[wave + 1];
    const int sub = lane >> 4;
    const int c16 = lane & 15;

    float a[8];
#pragma unroll
    for (int t = 0; t < 8; ++t) a[t] = 0.f;

    for (int ibase = beg; ibase < end; ibase += 16) {
#pragma unroll
        for (int j = 0; j < 4; ++j) {
            const int e = ibase + j * 4 + sub;
            bf16x8 v = {};
            if (e < end) {
                v = *reinterpret_cast<const bf16x8*>(
                    Xbf + (size_t)edge_src[e] * NFEAT + c16 * 8);
            }
#pragma unroll
            for (int t = 0; t < 8; ++t) a[t] += bf2f((unsigned short)v[t]);
        }
    }

#pragma unroll
    for (int t = 0; t < 8; ++t) {
        float x = a[t];
        x += __shfl_xor(x, 16, 64);
        x += __shfl_xor(x, 32, 64);
        a[t] = x;
    }

    if (sub == 0) {
        const float inv = 1.0f / fmaxf((float)(end - beg), 1.0f);
        uint4 o;
        o.x = pack2bf(a[0] * inv, a[1] * inv);
        o.y = pack2bf(a[2] * inv, a[3] * inv);
        o.z = pack2bf(a[4] * inv, a[5] * inv);
        o.w = pack2bf(a[6] * inv, a[7] * inv);
        reinterpret_cast<uint4*>(Mbf + (size_t)wave * NFEAT)[c16] = o;
    }
}

// ---------------------------------------------------------------------------
// MFMA GEMM: out = [relu]( [Xbf | Mbf] @ WcT^T + b ),  K=256, 16x16x32 bf16.
// 512 thr = 8 waves; full weight layer (64KB) in LDS with 16B-chunk XOR
// swizzle on both sides -> conflict-free ds_read_b128. A-frags in registers.
// ---------------------------------------------------------------------------
__global__ __launch_bounds__(512, 4) void mfma_gemm_kernel(
    const unsigned short* __restrict__ Xbf,
    const unsigned short* __restrict__ Mbf,
    const unsigned short* __restrict__ WcT,
    const float* __restrict__ bias,
    unsigned short* out_bf,
    float* out_f32,
    int n_nodes, int do_relu) {
    __shared__ unsigned short sW[128 * 256];  // 64 KB, swizzled

    const int tid = threadIdx.x;
    const int wave = tid >> 6;
    const int lane = tid & 63;

#pragma unroll
    for (int it = 0; it < 8; ++it) {
        int c = it * 512 + tid;
        int row = c >> 5;
        int ch = c & 31;
        bf16x8 v = *reinterpret_cast<const bf16x8*>(WcT + row * 256 + ch * 8);
        *reinterpret_cast<bf16x8*>(sW + row * 256 + ((ch ^ (row & 7)) << 3)) = v;
    }

    const int row_base = blockIdx.x * 128 + wave * 16;
    const int l15 = lane & 15;
    const int g = lane >> 4;
    const int kgrp = g * 8;

    const int arow = min(row_base + l15, n_nodes - 1);
    const unsigned short* Arow = Xbf + (size_t)arow * NFEAT;
    const unsigned short* Mrow = Mbf + (size_t)arow * NFEAT;
    bf16x8 afr[8];
#pragma unroll
    for (int s = 0; s < 4; ++s)
        afr[s] = *reinterpret_cast<const bf16x8*>(Arow + s * 32 + kgrp);
#pragma unroll
    for (int s = 0; s < 4; ++s)
        afr[4 + s] = *reinterpret_cast<const bf16x8*>(Mrow + s * 32 + kgrp);

    f32x4 acc[8];
#pragma unroll
    for (int t = 0; t < 8; ++t) acc[t] = (f32x4){0.f, 0.f, 0.f, 0.f};

    __syncthreads();

#pragma unroll
    for (int ks = 0; ks < 8; ++ks) {
        const int chunk_w = ks * 4 + g;
#pragma unroll
        for (int t = 0; t < 8; ++t) {
            const int j = t * 16 + l15;
            bf16x8 b = *reinterpret_cast<const bf16x8*>(
                sW + j * 256 + ((chunk_w ^ (j & 7)) << 3));
            acc[t] =
                __builtin_amdgcn_mfma_f32_16x16x32_bf16(afr[ks], b, acc[t], 0, 0, 0);
        }
    }

    const int crow0 = row_base + g * 4;
#pragma unroll
    for (int t = 0; t < 8; ++t) {
        const int c = t * 16 + l15;
        const float bj = bias[c];
#pragma unroll
        for (int r = 0; r < 4; ++r) {
            const int gr = crow0 + r;
            if (gr < n_nodes) {
                float v = acc[t][r] + bj;
                if (do_relu) v = fmaxf(v, 0.f);
                if (out_f32)
                    out_f32[(size_t)gr * NFEAT + c] = v;
                else
                    out_bf[(size_t)gr * NFEAT + c] = f2bf(v);
            }
        }
    }
}

extern "C" void kernel_launch(void* const* d_in, const int* in_sizes, int n_in,
                              void* d_out, int out_size, void* d_ws,
                              size_t ws_size, hipStream_t stream) {
    const float* h = (const float*)d_in[0];
    const int* src = (const int*)d_in[1];
    const int* dst = (const int*)d_in[2];
    const float* Ws0 = (const float*)d_in[3];
    const float* Wn0 = (const float*)d_in[4];
    const float* b0 = (const float*)d_in[5];
    const float* Ws1 = (const float*)d_in[6];
    const float* Wn1 = (const float*)d_in[7];
    const float* b1 = (const float*)d_in[8];
    float* out = (float*)d_out;

    const int n_nodes = in_sizes[0] / NFEAT;
    const int n_edges = in_sizes[1];
    const int B = (n_nodes + 127) >> 7;           // buckets (391 <= 512)
    const int nblkE = (n_edges + EPB - 1) / EPB;  // binning blocks (147)

    // workspace layout (~31 MB; ws is ~268 MB per harness poison fills)
    unsigned short* hbf = (unsigned short*)d_ws;          // [N,128] bf16 (+h1)
    unsigned short* Mbf = hbf + (size_t)n_nodes * NFEAT;  // [N,128] bf16
    unsigned short* WcT = Mbf + (size_t)n_nodes * NFEAT;  // 2*[128][256] bf16
    int* Hist = (int*)(WcT + 2 * 128 * 256);              // [nblkE][B]
    int* bucket_base = Hist + (size_t)nblkE * B;          // [B+1]
    unsigned int* Binned = (unsigned int*)(bucket_base + B + 1);  // [E]
    int* edge_src = (int*)(Binned + n_edges);             // [E]
    int* row_start = edge_src + n_edges;                  // [N+1]

    // ---- prep (convert + weights) ----
    const int n4 = n_nodes * NFEAT / 4;
    const int nw = 2 * 128 * 256;
    prep_kernel<<<(n4 + nw + 255) / 256, 256, 0, stream>>>(
        h, Ws0, Wn0, Ws1, Wn1, hbf, WcT, n4, nw);

    // ---- bucketed CSR build ----
    bin_hist_kernel<<<nblkE, 1024, 0, stream>>>(dst, Hist, n_edges, B);
    bin_scan_kernel<<<1, 512, 0, stream>>>(Hist, bucket_base, nblkE, B);
    bin_scatter_kernel<<<nblkE, 1024, 0, stream>>>(src, dst, Hist, Binned,
                                                   n_edges, B);
    csr_fill_kernel<<<B, 256, 0, stream>>>(Binned, bucket_base, edge_src,
                                           row_start, n_nodes);

    const int agg_blocks = (n_nodes * 64 + 255) / 256;
    const int gemm_blocks = (n_nodes + 127) / 128;

    // ---- layer 0 (h1 bf16 written in-place over hbf) ----
    aggregate_kernel<<<agg_blocks, 256, 0, stream>>>(hbf, row_start, edge_src,
                                                     Mbf, n_nodes);
    mfma_gemm_kernel<<<gemm_blocks, 512, 0, stream>>>(
        hbf, Mbf, WcT, b0, hbf, (float*)nullptr, n_nodes, 1);

    // ---- layer 1 (f32 out to d_out) ----
    aggregate_kernel<<<agg_blocks, 256, 0, stream>>>(hbf, row_start, edge_src,
                                                     Mbf, n_nodes);
    mfma_gemm_kernel<<<gemm_blocks, 512, 0, stream>>>(
        hbf, Mbf, WcT + 32768, b1, (unsigned short*)nullptr, out, n_nodes, 0);
}

// Round 10
// 133.524 us; speedup vs baseline: 8.4868x; 1.1470x over previous
//
#include <hip/hip_runtime.h>
#include <hip/hip_bf16.h>

#define NFEAT 128
#define EPB 4096  // edges per scatter block (1024 thr x 4)

typedef __attribute__((ext_vector_type(8))) short bf16x8;
typedef __attribute__((ext_vector_type(4))) float f32x4;

__device__ inline unsigned short f2bf(float f) {  // RNE f32 -> bf16
    unsigned int u = __float_as_uint(f);
    u += 0x7fffu + ((u >> 16) & 1u);
    return (unsigned short)(u >> 16);
}
__device__ inline unsigned int pack2bf(float lo, float hi) {
    return (unsigned int)f2bf(lo) | ((unsigned int)f2bf(hi) << 16);
}
__device__ inline float bf2f(unsigned short s) {
    return __uint_as_float(((unsigned int)s) << 16);
}

// ---------------------------------------------------------------------------
// zero small int buffer (bucket totals)
// ---------------------------------------------------------------------------
__global__ void zero_small(int* __restrict__ p, int n) {
    int i = blockIdx.x * blockDim.x + threadIdx.x;
    if (i < n) p[i] = 0;
}

// ---------------------------------------------------------------------------
// fused prep: convert h->bf16 | pack+transpose weights | bucket histogram
// (edge blocks do per-block LDS hist -> ~B global atomics per block)
// ---------------------------------------------------------------------------
__global__ __launch_bounds__(256) void prep_hist_kernel(
    const float* __restrict__ h, const float* __restrict__ Ws0,
    const float* __restrict__ Wn0, const float* __restrict__ Ws1,
    const float* __restrict__ Wn1, unsigned short* __restrict__ hbf,
    unsigned short* __restrict__ WcT, const int* __restrict__ dst,
    int* __restrict__ total, int n4, int nw, int n_edges, int B,
    int prep_blocks) {
    __shared__ int sH[512];
    if ((int)blockIdx.x < prep_blocks) {
        int i = blockIdx.x * 256 + threadIdx.x;
        if (i < n4) {
            float4 v = reinterpret_cast<const float4*>(h)[i];
            uint2 o;
            o.x = pack2bf(v.x, v.y);
            o.y = pack2bf(v.z, v.w);
            reinterpret_cast<uint2*>(hbf)[i] = o;
        } else if (i < n4 + nw) {
            int idx = i - n4;
            int layer = idx >> 15;
            int rem = idx & 32767;
            int j = rem >> 8;
            int k = rem & 255;
            const float* Ws = layer ? Ws1 : Ws0;
            const float* Wn = layer ? Wn1 : Wn0;
            float v = (k < 128) ? Ws[k * 128 + j] : Wn[(k - 128) * 128 + j];
            WcT[layer * 32768 + j * 256 + k] = f2bf(v);
        }
    } else {
        const int blk = blockIdx.x - prep_blocks;
        const int tid = threadIdx.x;
        for (int t = tid; t < 512; t += 256) sH[t] = 0;  // FULL clear (r9 bug)
        __syncthreads();
#pragma unroll
        for (int i = 0; i < 16; ++i) {
            int e = blk * EPB + i * 256 + tid;
            if (e < n_edges) atomicAdd(&sH[dst[e] >> 7], 1);
        }
        __syncthreads();
        for (int t = tid; t < B; t += 256)
            if (sH[t]) atomicAdd(&total[t], sH[t]);
    }
}

// ---------------------------------------------------------------------------
// single-block scan of bucket totals -> bucket_base[B+1], cursor init
// ---------------------------------------------------------------------------
__global__ __launch_bounds__(512) void bucket_scan_kernel(
    const int* __restrict__ total, int* __restrict__ bucket_base,
    int* __restrict__ cursor, int B) {
    __shared__ int s[512];
    const int b = threadIdx.x;
    int v = (b < B) ? total[b] : 0;
    s[b] = v;
    __syncthreads();
    for (int off = 1; off < 512; off <<= 1) {
        int t = (b >= off) ? s[b - off] : 0;
        __syncthreads();
        s[b] += t;
        __syncthreads();
    }
    if (b < B) {
        int excl = s[b] - v;
        bucket_base[b] = excl;
        cursor[b] = excl;
    }
    if (b == 511) bucket_base[B] = s[511];
}

// ---------------------------------------------------------------------------
// scatter packed records (dstlo<<20 | src) into bucket runs; per-block run
// slots claimed via one atomicAdd(cursor[b], blockCount) per (block,bucket).
// ---------------------------------------------------------------------------
__global__ __launch_bounds__(1024) void bin_scatter_kernel(
    const int* __restrict__ src, const int* __restrict__ dst,
    int* __restrict__ cursor, unsigned int* __restrict__ Binned, int n_edges,
    int B) {
    __shared__ int sH[512];
    __shared__ int sBase[512];
    __shared__ int sCnt[512];
    const int tid = threadIdx.x;
    const int blk = blockIdx.x;
    if (tid < 512) { sH[tid] = 0; sCnt[tid] = 0; }
    __syncthreads();
    int d[4], sv[4];
    bool ok[4];
#pragma unroll
    for (int i = 0; i < 4; ++i) {
        int e = blk * EPB + i * 1024 + tid;
        ok[i] = e < n_edges;
        if (ok[i]) {
            d[i] = dst[e];
            sv[i] = src[e];
            atomicAdd(&sH[d[i] >> 7], 1);
        }
    }
    __syncthreads();
    if (tid < B && sH[tid]) sBase[tid] = atomicAdd(&cursor[tid], sH[tid]);
    __syncthreads();
#pragma unroll
    for (int i = 0; i < 4; ++i) {
        if (ok[i]) {
            int b = d[i] >> 7;
            int r = atomicAdd(&sCnt[b], 1);
            Binned[sBase[b] + r] =
                (unsigned)sv[i] | ((unsigned)(d[i] & 127) << 20);
        }
    }
}

// ---------------------------------------------------------------------------
// per-bucket CSR fill: one block per bucket (128 nodes). LDS histogram over
// dstlo -> 128-wide scan -> row_start (coalesced) + edge_src scatter confined
// to this bucket's ~6KB run.
// ---------------------------------------------------------------------------
__global__ __launch_bounds__(256) void csr_fill_kernel(
    const unsigned int* __restrict__ Binned,
    const int* __restrict__ bucket_base, int* __restrict__ edge_src,
    int* __restrict__ row_start, int n_nodes) {
    __shared__ int sH[128];
    __shared__ int sS[128];
    __shared__ int sCur[128];
    const int tid = threadIdx.x;
    const int bkt = blockIdx.x;
    const int beg = bucket_base[bkt];
    const int end = bucket_base[bkt + 1];

    if (tid < 128) sH[tid] = 0;
    __syncthreads();
    for (int e = beg + tid; e < end; e += 256)
        atomicAdd(&sH[(Binned[e] >> 20) & 127], 1);
    __syncthreads();
    if (tid < 128) sS[tid] = sH[tid];
    __syncthreads();
    for (int off = 1; off < 128; off <<= 1) {
        int v = (tid >= off && tid < 128) ? sS[tid - off] : 0;
        __syncthreads();
        if (tid < 128) sS[tid] += v;
        __syncthreads();
    }
    if (tid < 128) {
        int excl = sS[tid] - sH[tid];
        sCur[tid] = excl;
        int gn = (bkt << 7) + tid;
        if (gn <= n_nodes) row_start[gn] = beg + excl;
    }
    __syncthreads();
    for (int e = beg + tid; e < end; e += 256) {
        unsigned rec = Binned[e];
        int pos = beg + atomicAdd(&sCur[(rec >> 20) & 127], 1);
        edge_src[pos] = (int)(rec & 0xFFFFF);
    }
}

// ---------------------------------------------------------------------------
// mean aggregation, high-MLP form: one wave per node; quarter-wave per row.
// 16 rows in flight per wave; 2-step shfl_xor reduce; sub==0 writes 256B row.
// ---------------------------------------------------------------------------
__global__ __launch_bounds__(256) void aggregate_kernel(
    const unsigned short* __restrict__ Xbf, const int* __restrict__ row_start,
    const int* __restrict__ edge_src, unsigned short* __restrict__ Mbf,
    int n_nodes) {
    const int wave = (blockIdx.x * blockDim.x + threadIdx.x) >> 6;
    const int lane = threadIdx.x & 63;
    if (wave >= n_nodes) return;
    const int beg = row_start[wave];
    const int end = row_start[wave + 1];
    const int sub = lane >> 4;
    const int c16 = lane & 15;

    float a[8];
#pragma unroll
    for (int t = 0; t < 8; ++t) a[t] = 0.f;

    for (int ibase = beg; ibase < end; ibase += 16) {
#pragma unroll
        for (int j = 0; j < 4; ++j) {
            const int e = ibase + j * 4 + sub;
            bf16x8 v = {};
            if (e < end) {
                v = *reinterpret_cast<const bf16x8*>(
                    Xbf + (size_t)edge_src[e] * NFEAT + c16 * 8);
            }
#pragma unroll
            for (int t = 0; t < 8; ++t) a[t] += bf2f((unsigned short)v[t]);
        }
    }

#pragma unroll
    for (int t = 0; t < 8; ++t) {
        float x = a[t];
        x += __shfl_xor(x, 16, 64);
        x += __shfl_xor(x, 32, 64);
        a[t] = x;
    }

    if (sub == 0) {
        const float inv = 1.0f / fmaxf((float)(end - beg), 1.0f);
        uint4 o;
        o.x = pack2bf(a[0] * inv, a[1] * inv);
        o.y = pack2bf(a[2] * inv, a[3] * inv);
        o.z = pack2bf(a[4] * inv, a[5] * inv);
        o.w = pack2bf(a[6] * inv, a[7] * inv);
        reinterpret_cast<uint4*>(Mbf + (size_t)wave * NFEAT)[c16] = o;
    }
}

// ---------------------------------------------------------------------------
// MFMA GEMM: out = [relu]( [Xbf | Mbf] @ WcT^T + b ),  K=256, 16x16x32 bf16.
// 512 thr = 8 waves; full weight layer (64KB) in LDS with 16B-chunk XOR
// swizzle on both sides -> conflict-free ds_read_b128. A-frags in registers.
// ---------------------------------------------------------------------------
__global__ __launch_bounds__(512, 4) void mfma_gemm_kernel(
    const unsigned short* __restrict__ Xbf,
    const unsigned short* __restrict__ Mbf,
    const unsigned short* __restrict__ WcT,
    const float* __restrict__ bias,
    unsigned short* out_bf,
    float* out_f32,
    int n_nodes, int do_relu) {
    __shared__ unsigned short sW[128 * 256];  // 64 KB, swizzled

    const int tid = threadIdx.x;
    const int wave = tid >> 6;
    const int lane = tid & 63;

#pragma unroll
    for (int it = 0; it < 8; ++it) {
        int c = it * 512 + tid;
        int row = c >> 5;
        int ch = c & 31;
        bf16x8 v = *reinterpret_cast<const bf16x8*>(WcT + row * 256 + ch * 8);
        *reinterpret_cast<bf16x8*>(sW + row * 256 + ((ch ^ (row & 7)) << 3)) = v;
    }

    const int row_base = blockIdx.x * 128 + wave * 16;
    const int l15 = lane & 15;
    const int g = lane >> 4;
    const int kgrp = g * 8;

    const int arow = min(row_base + l15, n_nodes - 1);
    const unsigned short* Arow = Xbf + (size_t)arow * NFEAT;
    const unsigned short* Mrow = Mbf + (size_t)arow * NFEAT;
    bf16x8 afr[8];
#pragma unroll
    for (int s = 0; s < 4; ++s)
        afr[s] = *reinterpret_cast<const bf16x8*>(Arow + s * 32 + kgrp);
#pragma unroll
    for (int s = 0; s < 4; ++s)
        afr[4 + s] = *reinterpret_cast<const bf16x8*>(Mrow + s * 32 + kgrp);

    f32x4 acc[8];
#pragma unroll
    for (int t = 0; t < 8; ++t) acc[t] = (f32x4){0.f, 0.f, 0.f, 0.f};

    __syncthreads();

#pragma unroll
    for (int ks = 0; ks < 8; ++ks) {
        const int chunk_w = ks * 4 + g;
#pragma unroll
        for (int t = 0; t < 8; ++t) {
            const int j = t * 16 + l15;
            bf16x8 b = *reinterpret_cast<const bf16x8*>(
                sW + j * 256 + ((chunk_w ^ (j & 7)) << 3));
            acc[t] =
                __builtin_amdgcn_mfma_f32_16x16x32_bf16(afr[ks], b, acc[t], 0, 0, 0);
        }
    }

    const int crow0 = row_base + g * 4;
#pragma unroll
    for (int t = 0; t < 8; ++t) {
        const int c = t * 16 + l15;
        const float bj = bias[c];
#pragma unroll
        for (int r = 0; r < 4; ++r) {
            const int gr = crow0 + r;
            if (gr < n_nodes) {
                float v = acc[t][r] + bj;
                if (do_relu) v = fmaxf(v, 0.f);
                if (out_f32)
                    out_f32[(size_t)gr * NFEAT + c] = v;
                else
                    out_bf[(size_t)gr * NFEAT + c] = f2bf(v);
            }
        }
    }
}

extern "C" void kernel_launch(void* const* d_in, const int* in_sizes, int n_in,
                              void* d_out, int out_size, void* d_ws,
                              size_t ws_size, hipStream_t stream) {
    const float* h = (const float*)d_in[0];
    const int* src = (const int*)d_in[1];
    const int* dst = (const int*)d_in[2];
    const float* Ws0 = (const float*)d_in[3];
    const float* Wn0 = (const float*)d_in[4];
    const float* b0 = (const float*)d_in[5];
    const float* Ws1 = (const float*)d_in[6];
    const float* Wn1 = (const float*)d_in[7];
    const float* b1 = (const float*)d_in[8];
    float* out = (float*)d_out;

    const int n_nodes = in_sizes[0] / NFEAT;
    const int n_edges = in_sizes[1];
    const int B = (n_nodes + 127) >> 7;           // buckets (391 <= 512)
    const int nblkE = (n_edges + EPB - 1) / EPB;  // edge blocks (147)

    // workspace layout (~31 MB)
    unsigned short* hbf = (unsigned short*)d_ws;          // [N,128] bf16 (+h1)
    unsigned short* Mbf = hbf + (size_t)n_nodes * NFEAT;  // [N,128] bf16
    unsigned short* WcT = Mbf + (size_t)n_nodes * NFEAT;  // 2*[128][256] bf16
    int* total = (int*)(WcT + 2 * 128 * 256);             // [B]
    int* bucket_base = total + B;                         // [B+1]
    int* cursor = bucket_base + B + 1;                    // [B]
    unsigned int* Binned = (unsigned int*)(cursor + B);   // [E]
    int* edge_src = (int*)(Binned + n_edges);             // [E]
    int* row_start = edge_src + n_edges;                  // [N+1]

    const int n4 = n_nodes * NFEAT / 4;
    const int nw = 2 * 128 * 256;
    const int prep_blocks = (n4 + nw + 255) / 256;

    // ---- prep + bucket histogram ----
    zero_small<<<(B + 511) / 512, 512, 0, stream>>>(total, B);
    prep_hist_kernel<<<prep_blocks + nblkE, 256, 0, stream>>>(
        h, Ws0, Wn0, Ws1, Wn1, hbf, WcT, dst, total, n4, nw, n_edges, B,
        prep_blocks);
    bucket_scan_kernel<<<1, 512, 0, stream>>>(total, bucket_base, cursor, B);
    bin_scatter_kernel<<<nblkE, 1024, 0, stream>>>(src, dst, cursor, Binned,
                                                   n_edges, B);
    csr_fill_kernel<<<B, 256, 0, stream>>>(Binned, bucket_base, edge_src,
                                           row_start, n_nodes);

    const int agg_blocks = (n_nodes * 64 + 255) / 256;
    const int gemm_blocks = (n_nodes + 127) / 128;

    // ---- layer 0 (h1 bf16 written in-place over hbf) ----
    aggregate_kernel<<<agg_blocks, 256, 0, stream>>>(hbf, row_start, edge_src,
                                                     Mbf, n_nodes);
    mfma_gemm_kernel<<<gemm_blocks, 512, 0, stream>>>(
        hbf, Mbf, WcT, b0, hbf, (float*)nullptr, n_nodes, 1);

    // ---- layer 1 (f32 out to d_out) ----
    aggregate_kernel<<<agg_blocks, 256, 0, stream>>>(hbf, row_start, edge_src,
                                                     Mbf, n_nodes);
    mfma_gemm_kernel<<<gemm_blocks, 512, 0, stream>>>(
        hbf, Mbf, WcT + 32768, b1, (unsigned short*)nullptr, out, n_nodes, 0);
}